// Round 5
// baseline (374.055 us; speedup 1.0000x reference)
//
#include <hip/hip_runtime.h>

// GraphAttention (e3nn-style) on MI355X — Round 5: bf16-packed LDS weights + 2 edges/thread.
// Round-4 lesson: weight delivery moved to the per-CU LDS port (uniform ds_read_b128,
// re-read by every wave; broadcast is within-wave only) -> LDS-port-bound at 17% VALUBusy.
// Fix (4x LDS cut): bf16-pack weights (8/read) and process R=2 edges per thread
// (each read feeds 2 edges). tv3 moves to edge_v_a, handed off via bf16 buffer.
//
// Dims: M0=16 M1=8 Q0=8 Q1=4 O0=16 O1=8 EDGE_BASIS=16 HIDDEN=32
// TPK [32][320]: w1[0,128) w2[128,192) w3[192,256) w4[256,288) w5[288,320)
// TPV [32][640]: w1[0,256) w2[256,384) w3[384,512) w4[512,576) w5[576,640)
//
// ws (4B units): qd[N*20] | cnt[N] | start[N+1] | cursor[N] | flag | pad |
//                exbuf[E] | sabuf[E] | posbuf[E] | t3buf[E*4 uints] | vbuf[E*40]

#define BS 256

__device__ __forceinline__ float silu_f(float x) {
    return x * (1.0f / (1.0f + __expf(-x)));
}
__device__ __forceinline__ unsigned short f2b(float f) {   // f32 -> bf16 (RNE)
    unsigned u = __float_as_uint(f);
    u += 0x7fffu + ((u >> 16) & 1u);
    return (unsigned short)(u >> 16);
}
__device__ __forceinline__ unsigned pack2(float a, float b) {
    return ((unsigned)f2b(b) << 16) | (unsigned)f2b(a);
}
__device__ __forceinline__ void up2(unsigned u, float& a, float& b) {
    a = __uint_as_float(u << 16);
    b = __uint_as_float(u & 0xffff0000u);
}
// 8 bf16 weights -> FMA into 8 accumulators for two edges (ta/tb premultiplied)
__device__ __forceinline__ void fma8(const uint4 p, const float ta, const float tb,
                                     float* __restrict__ aA, float* __restrict__ aB) {
    float w;
    w = __uint_as_float(p.x << 16);          aA[0] += ta*w; aB[0] += tb*w;
    w = __uint_as_float(p.x & 0xffff0000u);  aA[1] += ta*w; aB[1] += tb*w;
    w = __uint_as_float(p.y << 16);          aA[2] += ta*w; aB[2] += tb*w;
    w = __uint_as_float(p.y & 0xffff0000u);  aA[3] += ta*w; aB[3] += tb*w;
    w = __uint_as_float(p.z << 16);          aA[4] += ta*w; aB[4] += tb*w;
    w = __uint_as_float(p.z & 0xffff0000u);  aA[5] += ta*w; aB[5] += tb*w;
    w = __uint_as_float(p.w << 16);          aA[6] += ta*w; aB[6] += tb*w;
    w = __uint_as_float(p.w & 0xffff0000u);  aA[7] += ta*w; aB[7] += tb*w;
}
__device__ __forceinline__ void fma4(const uint2 p, const float ta, const float tb,
                                     float* __restrict__ aA, float* __restrict__ aB) {
    float w;
    w = __uint_as_float(p.x << 16);          aA[0] += ta*w; aB[0] += tb*w;
    w = __uint_as_float(p.x & 0xffff0000u);  aA[1] += ta*w; aB[1] += tb*w;
    w = __uint_as_float(p.y << 16);          aA[2] += ta*w; aB[2] += tb*w;
    w = __uint_as_float(p.y & 0xffff0000u);  aA[3] += ta*w; aB[3] += tb*w;
}

__global__ __launch_bounds__(256) void node_pre(
    const float* __restrict__ node_ft,
    const int*   __restrict__ ei,
    const float* __restrict__ w_q_s, const float* __restrict__ w_q_v,
    const float* __restrict__ wdot_s, const float* __restrict__ wdot_v,
    float* __restrict__ qd, int* __restrict__ cnt, int* __restrict__ flag,
    int N, int E)
{
    const int n = blockIdx.x * blockDim.x + threadIdx.x;
    if (n == 0) {
        int acc = 0;
        const int kmax = (E < 64) ? E : 64;
        for (int k = 0; k < kmax; ++k) acc |= ei[2*k + 1];
        *flag = (acc == 0) ? 1 : 0;   // int64 layout => odd words all zero
    }
    if (n >= N) return;
    cnt[n] = 0;

    const float* nf = node_ft + (size_t)n * 40;
    float xs[16];
#pragma unroll
    for (int i = 0; i < 16; ++i) xs[i] = nf[i];
    float q[8];
#pragma unroll
    for (int o = 0; o < 8; ++o) {
        float a = 0.f;
#pragma unroll
        for (int i = 0; i < 16; ++i) a += xs[i] * w_q_s[i*8 + o];
        q[o] = a * 0.25f;
    }
    float* qdn = qd + (size_t)n * 20;
#pragma unroll
    for (int j = 0; j < 8; ++j) {
        float a = 0.f;
#pragma unroll
        for (int i = 0; i < 8; ++i) a += q[i] * wdot_s[i*8 + j];
        qdn[j] = a;
    }
    float xv[8][3];
#pragma unroll
    for (int i = 0; i < 8; ++i)
#pragma unroll
        for (int c = 0; c < 3; ++c) xv[i][c] = nf[16 + i*3 + c];
    float qv[4][3];
#pragma unroll
    for (int o = 0; o < 4; ++o)
#pragma unroll
        for (int c = 0; c < 3; ++c) {
            float a = 0.f;
#pragma unroll
            for (int i = 0; i < 8; ++i) a += xv[i][c] * w_q_v[i*4 + o];
            qv[o][c] = a * 0.35355339059327379f;
        }
#pragma unroll
    for (int j = 0; j < 4; ++j)
#pragma unroll
        for (int c = 0; c < 3; ++c) {
            float a = 0.f;
#pragma unroll
            for (int i = 0; i < 4; ++i) a += qv[i][c] * wdot_v[i*4 + j];
            qdn[8 + j*3 + c] = a;
        }
}

__global__ __launch_bounds__(256) void count_edges(
    const int* __restrict__ ei, int* __restrict__ cnt,
    const int* __restrict__ flag, int E)
{
    const int e = blockIdx.x * blockDim.x + threadIdx.x;
    if (e >= E) return;
    const int is64 = *flag;
    const int rcv = is64 ? ei[2*(E + e)] : ei[E + e];
    atomicAdd(cnt + rcv, 1);
}

__global__ __launch_bounds__(1024) void scan_kernel(
    const int* __restrict__ cnt, int* __restrict__ start,
    int* __restrict__ cursor, int N)
{
    __shared__ int wsum[16];
    __shared__ int s_carry;
    const int tid = threadIdx.x, wave = tid >> 6, lane = tid & 63;
    if (tid == 0) s_carry = 0;
    __syncthreads();
    for (int base = 0; base < N; base += 1024) {
        const int i = base + tid;
        const int v = (i < N) ? cnt[i] : 0;
        int x = v;
#pragma unroll
        for (int d = 1; d < 64; d <<= 1) {
            const int y = __shfl_up(x, d, 64);
            if (lane >= d) x += y;
        }
        if (lane == 63) wsum[wave] = x;
        __syncthreads();
        if (wave == 0 && lane < 16) {
            int w = wsum[lane];
#pragma unroll
            for (int d = 1; d < 16; d <<= 1) {
                const int y = __shfl_up(w, d, 64);
                if (lane >= d) w += y;
            }
            wsum[lane] = w;
        }
        __syncthreads();
        const int woff = (wave == 0) ? 0 : wsum[wave - 1];
        const int carry = s_carry;
        if (i < N) {
            const int s = carry + woff + x - v;
            start[i] = s;
            cursor[i] = s;
        }
        __syncthreads();
        if (tid == 0) s_carry = carry + wsum[15];
        __syncthreads();
    }
    if (tid == 0) start[N] = s_carry;
}

// ===================== edge_k: K-side TP + dot -> sa/ex/pos =====================
__global__ __launch_bounds__(BS, 1) void edge_k(
    const float* __restrict__ node_ft,
    const int*   __restrict__ ei,
    const float* __restrict__ edge_sh,
    const float* __restrict__ edge_scalars,
    const float* __restrict__ fck_w1,       // [16,32] global (s_load, 2 KB)
    const float* __restrict__ fck_w2,       // [32,320] -> LDS bf16
    const float* __restrict__ qd,
    int*   __restrict__ cursor,
    float* __restrict__ exbuf,              // [E] CSR order
    float* __restrict__ sabuf,              // [E] edge order
    int*   __restrict__ posbuf,             // [E] edge order
    const int* __restrict__ flag,
    int N, int E)
{
    __shared__ unsigned sW[32 * 160];       // 320 cols bf16-pair-packed: 20 KB
    __shared__ unsigned s_xs[16][BS];       // 16 KB (2 edges packed per uint)
    __shared__ unsigned s_xv[24][BS];       // 24 KB ([c*8+i])

    const int tid = threadIdx.x;
    {
        const float2* g2 = (const float2*)fck_w2;      // contiguous [32*160] float2
        for (int idx = tid; idx < 32 * 160; idx += BS) {
            const float2 w = g2[idx];
            sW[idx] = pack2(w.x, w.y);
        }
    }

    const int base = blockIdx.x * (2 * BS);
    const int e0 = base + tid, e1 = e0 + BS;
    const bool v0 = (e0 < E), v1 = (e1 < E);
    const int e0c = v0 ? e0 : 0, e1c = v1 ? e1 : 0;

    const int is64 = *flag;
    const int snd0 = is64 ? ei[2*e0c] : ei[e0c];
    const int rcv0 = is64 ? ei[2*(E + e0c)] : ei[E + e0c];
    const int snd1 = is64 ? ei[2*e1c] : ei[e1c];
    const int rcv1 = is64 ? ei[2*(E + e1c)] : ei[E + e1c];

    int pos0 = 0, pos1 = 0;                   // early atomics: hide under FMAs
    if (v0) pos0 = atomicAdd(cursor + rcv0, 1);
    if (v1) pos1 = atomicAdd(cursor + rcv1, 1);

    const float4 shA = *(const float4*)(edge_sh + (size_t)e0c * 4);
    const float4 shB = *(const float4*)(edge_sh + (size_t)e1c * 4);

    {
        const float4* nfa = (const float4*)(node_ft + (size_t)snd0 * 40);
        const float4* nfb = (const float4*)(node_ft + (size_t)snd1 * 40);
        float xa[40], xb[40];
#pragma unroll
        for (int t = 0; t < 10; ++t) {
            const float4 a = nfa[t], b = nfb[t];
            xa[4*t+0]=a.x; xa[4*t+1]=a.y; xa[4*t+2]=a.z; xa[4*t+3]=a.w;
            xb[4*t+0]=b.x; xb[4*t+1]=b.y; xb[4*t+2]=b.z; xb[4*t+3]=b.w;
        }
#pragma unroll
        for (int i = 0; i < 16; ++i) s_xs[i][tid] = pack2(xa[i], xb[i]);
#pragma unroll
        for (int i = 0; i < 8; ++i)
#pragma unroll
            for (int c = 0; c < 3; ++c)
                s_xv[c*8 + i][tid] = pack2(xa[16 + i*3 + c], xb[16 + i*3 + c]);
    }
    __syncthreads();   // weights + columns staged; no barriers after

    float esA[16], esB[16];
    {
        const float4* ea = (const float4*)(edge_scalars + (size_t)e0c * 16);
        const float4* eb = (const float4*)(edge_scalars + (size_t)e1c * 16);
#pragma unroll
        for (int t = 0; t < 4; ++t) {
            const float4 a = ea[t], b = eb[t];
            esA[4*t+0]=a.x; esA[4*t+1]=a.y; esA[4*t+2]=a.z; esA[4*t+3]=a.w;
            esB[4*t+0]=b.x; esB[4*t+1]=b.y; esB[4*t+2]=b.z; esB[4*t+3]=b.w;
        }
    }
    float hka[32], hkb[32];
#pragma unroll
    for (int j = 0; j < 32; ++j) {
        float a = 0.f, b = 0.f;
#pragma unroll
        for (int t = 0; t < 16; ++t) {
            const float w = fck_w1[t*32 + j];
            a += esA[t] * w; b += esB[t] * w;
        }
        hka[j] = silu_f(a * 0.25f);
        hkb[j] = silu_f(b * 0.25f);
    }

    const uint4* sW4 = (const uint4*)sW;    // 40 uint4 per j-row
    const uint2* sW2 = (const uint2*)sW;    // 80 uint2 per j-row

    float tk1a[8]={}, tk1b[8]={}, tk3a[4]={}, tk3b[4]={};
#pragma unroll 1
    for (int i = 0; i < 16; ++i) {
        float xa_, xb_; up2(s_xs[i][tid], xa_, xb_);
#pragma unroll
        for (int j = 0; j < 32; ++j) {
            const float ta = xa_ * hka[j], tb = xb_ * hkb[j];
            fma8(sW4[j*40 + i],      ta, tb, tk1a, tk1b);       // cols i*8
            fma4(sW2[j*80 + 48 + i], ta, tb, tk3a, tk3b);       // cols 192+i*4
        }
    }

    float tk2a[8]={}, tk2b[8]={};
#pragma unroll 1
    for (int i = 0; i < 8; ++i) {
        float x0a,x0b,x1a,x1b,x2a,x2b;
        up2(s_xv[i][tid],      x0a, x0b);
        up2(s_xv[8 + i][tid],  x1a, x1b);
        up2(s_xv[16 + i][tid], x2a, x2b);
        const float pva = (x0a*shA.y + x1a*shA.z + x2a*shA.w) * 0.57735026918962576f;
        const float pvb = (x0b*shB.y + x1b*shB.z + x2b*shB.w) * 0.57735026918962576f;
#pragma unroll
        for (int j = 0; j < 32; ++j)
            fma8(sW4[j*40 + 16 + i], pva*hka[j], pvb*hkb[j], tk2a, tk2b);  // cols 128+i*8
    }

    float tk4a[12]={}, tk4b[12]={}, tk5a[12]={}, tk5b[12]={};
#pragma unroll 1
    for (int i = 0; i < 8; ++i) {
        float w4a[4]={}, w4b[4]={}, w5a[4]={}, w5b[4]={};
#pragma unroll
        for (int j = 0; j < 32; ++j) {
            fma4(sW2[j*80 + 64 + i], hka[j], hkb[j], w4a, w4b); // cols 256+i*4
            fma4(sW2[j*80 + 72 + i], hka[j], hkb[j], w5a, w5b); // cols 288+i*4
        }
        float x0a,x0b,x1a,x1b,x2a,x2b;
        up2(s_xv[i][tid],      x0a, x0b);
        up2(s_xv[8 + i][tid],  x1a, x1b);
        up2(s_xv[16 + i][tid], x2a, x2b);
#pragma unroll
        for (int o = 0; o < 4; ++o) {
            tk4a[o*3+0] += x0a*w4a[o]; tk4a[o*3+1] += x1a*w4a[o]; tk4a[o*3+2] += x2a*w4a[o];
            tk4b[o*3+0] += x0b*w4b[o]; tk4b[o*3+1] += x1b*w4b[o]; tk4b[o*3+2] += x2b*w4b[o];
            tk5a[o*3+0] += x0a*w5a[o]; tk5a[o*3+1] += x1a*w5a[o]; tk5a[o*3+2] += x2a*w5a[o];
            tk5b[o*3+0] += x0b*w5b[o]; tk5b[o*3+1] += x1b*w5b[o]; tk5b[o*3+2] += x2b*w5b[o];
        }
    }

    float qA[20], qB[20];
    {
        const float4* qa = (const float4*)(qd + (size_t)rcv0 * 20);
        const float4* qb = (const float4*)(qd + (size_t)rcv1 * 20);
#pragma unroll
        for (int t = 0; t < 5; ++t) {
            const float4 a = qa[t], b = qb[t];
            qA[4*t+0]=a.x; qA[4*t+1]=a.y; qA[4*t+2]=a.z; qA[4*t+3]=a.w;
            qB[4*t+0]=b.x; qB[4*t+1]=b.y; qB[4*t+2]=b.z; qB[4*t+3]=b.w;
        }
    }
    const float CS = 4.0343567508008e-3f;   // 1/sqrt(32)/sqrt(24)/sqrt(80)
    const float CV = 2.0171788261497e-3f;   // (1/32)*(1/sqrt3)/sqrt(80)

    float dotsA = 0.f, dotvA = 0.f, dotsB = 0.f, dotvB = 0.f;
#pragma unroll
    for (int o = 0; o < 8; ++o) {
        dotsA += qA[o] * (shA.x*tk1a[o] + tk2a[o]);
        dotsB += qB[o] * (shB.x*tk1b[o] + tk2b[o]);
    }
    const float svA[3] = {shA.y, shA.z, shA.w};
    const float svB[3] = {shB.y, shB.z, shB.w};
#pragma unroll
    for (int o = 0; o < 4; ++o)
#pragma unroll
        for (int c = 0; c < 3; ++c) {
            const int c1 = (c+1) % 3, c2 = (c+2) % 3;
            const float kva = tk3a[o]*svA[c] + shA.x*tk4a[o*3+c]
                + (svA[c2]*tk5a[o*3+c1] - svA[c1]*tk5a[o*3+c2]) * 0.70710678118654752f;
            const float kvb = tk3b[o]*svB[c] + shB.x*tk4b[o*3+c]
                + (svB[c2]*tk5b[o*3+c1] - svB[c1]*tk5b[o*3+c2]) * 0.70710678118654752f;
            dotvA += qA[8 + o*3 + c] * kva;
            dotvB += qB[8 + o*3 + c] * kvb;
        }
    const float dotA = dotsA * CS + dotvA * CV;
    const float dotB = dotsB * CS + dotvB * CV;
    const float saA = __expf(0.5f * dotA);
    const float saB = __expf(0.5f * dotB);

    if (v0) { exbuf[pos0] = saA * saA; sabuf[e0] = saA; posbuf[e0] = pos0; }
    if (v1) { exbuf[pos1] = saB * saB; sabuf[e1] = saB; posbuf[e1] = pos1; }
}

// ===================== edge_v_a: V cols [0,512) -> rows [0,16) + tv3 handoff =====================
__global__ __launch_bounds__(BS, 1) void edge_v_a(
    const float* __restrict__ node_ft,
    const int*   __restrict__ ei,
    const float* __restrict__ edge_sh,
    const float* __restrict__ edge_scalars,
    const float* __restrict__ fcv_w1,
    const float* __restrict__ fcv_w2,
    const float* __restrict__ sabuf,
    const int*   __restrict__ posbuf,
    unsigned* __restrict__ t3buf,           // [E,4] bf16-packed tv3
    float* __restrict__ vbuf,               // [E,40]
    const int* __restrict__ flag,
    int E)
{
    __shared__ unsigned sW[32 * 256];       // cols [0,512) bf16-packed: 32 KB
    __shared__ unsigned s_xs[16][BS];       // 16 KB
    __shared__ unsigned s_pv[8][BS];        // 8 KB

    const int tid = threadIdx.x;
    {
        const float2* g2 = (const float2*)fcv_w2;      // 320 float2 per row
        for (int idx = tid; idx < 32 * 256; idx += BS) {
            const int j = idx >> 8, cp = idx & 255;
            const float2 w = g2[j*320 + cp];
            sW[idx] = pack2(w.x, w.y);
        }
    }

    const int base = blockIdx.x * (2 * BS);
    const int e0 = base + tid, e1 = e0 + BS;
    const bool v0 = (e0 < E), v1 = (e1 < E);
    const int e0c = v0 ? e0 : 0, e1c = v1 ? e1 : 0;

    const int is64 = *flag;
    const int snd0 = is64 ? ei[2*e0c] : ei[e0c];
    const int snd1 = is64 ? ei[2*e1c] : ei[e1c];

    const float4 shA = *(const float4*)(edge_sh + (size_t)e0c * 4);
    const float4 shB = *(const float4*)(edge_sh + (size_t)e1c * 4);

    const float saA = sabuf[e0c], saB = sabuf[e1c];   // early loads
    const int posA = posbuf[e0c], posB = posbuf[e1c];

    {
        const float4* nfa = (const float4*)(node_ft + (size_t)snd0 * 40);
        const float4* nfb = (const float4*)(node_ft + (size_t)snd1 * 40);
        float xa[40], xb[40];
#pragma unroll
        for (int t = 0; t < 10; ++t) {
            const float4 a = nfa[t], b = nfb[t];
            xa[4*t+0]=a.x; xa[4*t+1]=a.y; xa[4*t+2]=a.z; xa[4*t+3]=a.w;
            xb[4*t+0]=b.x; xb[4*t+1]=b.y; xb[4*t+2]=b.z; xb[4*t+3]=b.w;
        }
#pragma unroll
        for (int i = 0; i < 16; ++i) s_xs[i][tid] = pack2(xa[i], xb[i]);
#pragma unroll
        for (int i = 0; i < 8; ++i) {
            const float pa = (xa[16+i*3]*shA.y + xa[17+i*3]*shA.z + xa[18+i*3]*shA.w)
                             * 0.57735026918962576f;
            const float pb = (xb[16+i*3]*shB.y + xb[17+i*3]*shB.z + xb[18+i*3]*shB.w)
                             * 0.57735026918962576f;
            s_pv[i][tid] = pack2(pa, pb);
        }
    }
    __syncthreads();

    float esA[16], esB[16];
    {
        const float4* ea = (const float4*)(edge_scalars + (size_t)e0c * 16);
        const float4* eb = (const float4*)(edge_scalars + (size_t)e1c * 16);
#pragma unroll
        for (int t = 0; t < 4; ++t) {
            const float4 a = ea[t], b = eb[t];
            esA[4*t+0]=a.x; esA[4*t+1]=a.y; esA[4*t+2]=a.z; esA[4*t+3]=a.w;
            esB[4*t+0]=b.x; esB[4*t+1]=b.y; esB[4*t+2]=b.z; esB[4*t+3]=b.w;
        }
    }
    float hva[32], hvb[32];
#pragma unroll
    for (int j = 0; j < 32; ++j) {
        float a = 0.f, b = 0.f;
#pragma unroll
        for (int t = 0; t < 16; ++t) {
            const float w = fcv_w1[t*32 + j];
            a += esA[t] * w; b += esB[t] * w;
        }
        hva[j] = silu_f(a * 0.25f);
        hvb[j] = silu_f(b * 0.25f);
    }

    const uint4* sW4 = (const uint4*)sW;    // 64 uint4 per j-row

    float tv1a[16]={}, tv1b[16]={}, tv3a[8]={}, tv3b[8]={};
#pragma unroll 1
    for (int i = 0; i < 16; ++i) {
        float xa_, xb_; up2(s_xs[i][tid], xa_, xb_);
#pragma unroll
        for (int j = 0; j < 32; ++j) {
            const float ta = xa_ * hva[j], tb = xb_ * hvb[j];
            fma8(sW4[j*64 + 2*i],     ta, tb, tv1a,     tv1b);      // cols i*16
            fma8(sW4[j*64 + 2*i + 1], ta, tb, tv1a + 8, tv1b + 8);  // cols i*16+8
            fma8(sW4[j*64 + 48 + i],  ta, tb, tv3a,     tv3b);      // cols 384+i*8
        }
    }

    float tv2a[16]={}, tv2b[16]={};
#pragma unroll 1
    for (int i = 0; i < 8; ++i) {
        float pa, pb; up2(s_pv[i][tid], pa, pb);
#pragma unroll
        for (int j = 0; j < 32; ++j) {
            const float ta = pa * hva[j], tb = pb * hvb[j];
            fma8(sW4[j*64 + 32 + 2*i],     ta, tb, tv2a,     tv2b);     // cols 256+i*16
            fma8(sW4[j*64 + 32 + 2*i + 1], ta, tb, tv2a + 8, tv2b + 8); // +8
        }
    }

    const float cs_out = 0.03608439182435161f;   // (1/sqrt32)*(1/sqrt24)
    if (v0) {
        float4* vp = (float4*)(vbuf + (size_t)posA * 40);
#pragma unroll
        for (int t = 0; t < 4; ++t) {
            float4 r;
            r.x = saA * (shA.x*tv1a[4*t+0] + tv2a[4*t+0]) * cs_out;
            r.y = saA * (shA.x*tv1a[4*t+1] + tv2a[4*t+1]) * cs_out;
            r.z = saA * (shA.x*tv1a[4*t+2] + tv2a[4*t+2]) * cs_out;
            r.w = saA * (shA.x*tv1a[4*t+3] + tv2a[4*t+3]) * cs_out;
            vp[t] = r;
        }
        uint4 t3;
        t3.x = pack2(tv3a[0], tv3a[1]); t3.y = pack2(tv3a[2], tv3a[3]);
        t3.z = pack2(tv3a[4], tv3a[5]); t3.w = pack2(tv3a[6], tv3a[7]);
        *(uint4*)(t3buf + (size_t)e0 * 4) = t3;
    }
    if (v1) {
        float4* vp = (float4*)(vbuf + (size_t)posB * 40);
#pragma unroll
        for (int t = 0; t < 4; ++t) {
            float4 r;
            r.x = saB * (shB.x*tv1b[4*t+0] + tv2b[4*t+0]) * cs_out;
            r.y = saB * (shB.x*tv1b[4*t+1] + tv2b[4*t+1]) * cs_out;
            r.z = saB * (shB.x*tv1b[4*t+2] + tv2b[4*t+2]) * cs_out;
            r.w = saB * (shB.x*tv1b[4*t+3] + tv2b[4*t+3]) * cs_out;
            vp[t] = r;
        }
        uint4 t3;
        t3.x = pack2(tv3b[0], tv3b[1]); t3.y = pack2(tv3b[2], tv3b[3]);
        t3.z = pack2(tv3b[4], tv3b[5]); t3.w = pack2(tv3b[6], tv3b[7]);
        *(uint4*)(t3buf + (size_t)e1 * 4) = t3;
    }
}

// ===================== edge_v_b: V cols [512,640) + tv3 -> rows [16,40) =====================
__global__ __launch_bounds__(BS, 1) void edge_v_b(
    const float* __restrict__ node_ft,
    const int*   __restrict__ ei,
    const float* __restrict__ edge_sh,
    const float* __restrict__ edge_scalars,
    const float* __restrict__ fcv_w1,
    const float* __restrict__ fcv_w2,
    const float* __restrict__ sabuf,
    const int*   __restrict__ posbuf,
    const unsigned* __restrict__ t3buf,
    float* __restrict__ vbuf,
    const int* __restrict__ flag,
    int E)
{
    __shared__ unsigned sW[32 * 64];        // cols [512,640): 8 KB
    __shared__ unsigned s_xv[24][BS];       // 24 KB

    const int tid = threadIdx.x;
    {
        const float2* g2 = (const float2*)fcv_w2;
        for (int idx = tid; idx < 32 * 64; idx += BS) {
            const int j = idx >> 6, cp = idx & 63;
            const float2 w = g2[j*320 + 256 + cp];
            sW[idx] = pack2(w.x, w.y);
        }
    }

    const int base = blockIdx.x * (2 * BS);
    const int e0 = base + tid, e1 = e0 + BS;
    const bool v0 = (e0 < E), v1 = (e1 < E);
    const int e0c = v0 ? e0 : 0, e1c = v1 ? e1 : 0;

    const int is64 = *flag;
    const int snd0 = is64 ? ei[2*e0c] : ei[e0c];
    const int snd1 = is64 ? ei[2*e1c] : ei[e1c];

    const float4 shA = *(const float4*)(edge_sh + (size_t)e0c * 4);
    const float4 shB = *(const float4*)(edge_sh + (size_t)e1c * 4);
    const float saA = sabuf[e0c], saB = sabuf[e1c];
    const int posA = posbuf[e0c], posB = posbuf[e1c];
    const uint4 t3pA = *(const uint4*)(t3buf + (size_t)e0c * 4);
    const uint4 t3pB = *(const uint4*)(t3buf + (size_t)e1c * 4);

    {
        const float4* nfa = (const float4*)(node_ft + (size_t)snd0 * 40);
        const float4* nfb = (const float4*)(node_ft + (size_t)snd1 * 40);
        float xa[24], xb[24];
#pragma unroll
        for (int t = 4; t < 10; ++t) {
            const float4 a = nfa[t], b = nfb[t];
            xa[4*t-16]=a.x; xa[4*t-15]=a.y; xa[4*t-14]=a.z; xa[4*t-13]=a.w;
            xb[4*t-16]=b.x; xb[4*t-15]=b.y; xb[4*t-14]=b.z; xb[4*t-13]=b.w;
        }
#pragma unroll
        for (int i = 0; i < 8; ++i)
#pragma unroll
            for (int c = 0; c < 3; ++c)
                s_xv[c*8 + i][tid] = pack2(xa[i*3 + c], xb[i*3 + c]);
    }
    __syncthreads();

    float esA[16], esB[16];
    {
        const float4* ea = (const float4*)(edge_scalars + (size_t)e0c * 16);
        const float4* eb = (const float4*)(edge_scalars + (size_t)e1c * 16);
#pragma unroll
        for (int t = 0; t < 4; ++t) {
            const float4 a = ea[t], b = eb[t];
            esA[4*t+0]=a.x; esA[4*t+1]=a.y; esA[4*t+2]=a.z; esA[4*t+3]=a.w;
            esB[4*t+0]=b.x; esB[4*t+1]=b.y; esB[4*t+2]=b.z; esB[4*t+3]=b.w;
        }
    }
    float hva[32], hvb[32];
#pragma unroll
    for (int j = 0; j < 32; ++j) {
        float a = 0.f, b = 0.f;
#pragma unroll
        for (int t = 0; t < 16; ++t) {
            const float w = fcv_w1[t*32 + j];
            a += esA[t] * w; b += esB[t] * w;
        }
        hva[j] = silu_f(a * 0.25f);
        hvb[j] = silu_f(b * 0.25f);
    }

    const uint4* sW4 = (const uint4*)sW;    // 16 uint4 per j-row

    float tv4a[24]={}, tv4b[24]={}, tv5a[24]={}, tv5b[24]={};
#pragma unroll 1
    for (int i = 0; i < 8; ++i) {
        float w4a[8]={}, w4b[8]={}, w5a[8]={}, w5b[8]={};
#pragma unroll
        for (int j = 0; j < 32; ++j) {
            fma8(sW4[j*16 + i],     hva[j], hvb[j], w4a, w4b);   // cols 512+i*8
            fma8(sW4[j*16 + 8 + i], hva[j], hvb[j], w5a, w5b);   // cols 576+i*8
        }
        float x0a,x0b,x1a,x1b,x2a,x2b;
        up2(s_xv[i][tid],      x0a, x0b);
        up2(s_xv[8 + i][tid],  x1a, x1b);
        up2(s_xv[16 + i][tid], x2a, x2b);
#pragma unroll
        for (int o = 0; o < 8; ++o) {
            tv4a[o*3+0] += x0a*w4a[o]; tv4a[o*3+1] += x1a*w4a[o]; tv4a[o*3+2] += x2a*w4a[o];
            tv4b[o*3+0] += x0b*w4b[o]; tv4b[o*3+1] += x1b*w4b[o]; tv4b[o*3+2] += x2b*w4b[o];
            tv5a[o*3+0] += x0a*w5a[o]; tv5a[o*3+1] += x1a*w5a[o]; tv5a[o*3+2] += x2a*w5a[o];
            tv5b[o*3+0] += x0b*w5b[o]; tv5b[o*3+1] += x1b*w5b[o]; tv5b[o*3+2] += x2b*w5b[o];
        }
    }

    float t3A[8], t3B[8];
    up2(t3pA.x, t3A[0], t3A[1]); up2(t3pA.y, t3A[2], t3A[3]);
    up2(t3pA.z, t3A[4], t3A[5]); up2(t3pA.w, t3A[6], t3A[7]);
    up2(t3pB.x, t3B[0], t3B[1]); up2(t3pB.y, t3B[2], t3B[3]);
    up2(t3pB.z, t3B[4], t3B[5]); up2(t3pB.w, t3B[6], t3B[7]);

    const float svA[3] = {shA.y, shA.z, shA.w};
    const float svB[3] = {shB.y, shB.z, shB.w};
    if (v0) {
        float row[24];
#pragma unroll
        for (int o = 0; o < 8; ++o)
#pragma unroll
            for (int c = 0; c < 3; ++c) {
                const int c1 = (c+1) % 3, c2 = (c+2) % 3;
                const float vv = (t3A[o]*svA[c] + shA.x*tv4a[o*3+c]
                    + (svA[c2]*tv5a[o*3+c1] - svA[c1]*tv5a[o*3+c2]) * 0.70710678118654752f)
                    * 0.03125f;
                row[o*3 + c] = saA * vv;
            }
        float4* vp = (float4*)(vbuf + (size_t)posA * 40 + 16);
#pragma unroll
        for (int t = 0; t < 6; ++t) {
            float4 r; r.x=row[4*t+0]; r.y=row[4*t+1]; r.z=row[4*t+2]; r.w=row[4*t+3];
            vp[t] = r;
        }
    }
    if (v1) {
        float row[24];
#pragma unroll
        for (int o = 0; o < 8; ++o)
#pragma unroll
            for (int c = 0; c < 3; ++c) {
                const int c1 = (c+1) % 3, c2 = (c+2) % 3;
                const float vv = (t3B[o]*svB[c] + shB.x*tv4b[o*3+c]
                    + (svB[c2]*tv5b[o*3+c1] - svB[c1]*tv5b[o*3+c2]) * 0.70710678118654752f)
                    * 0.03125f;
                row[o*3 + c] = saB * vv;
            }
        float4* vp = (float4*)(vbuf + (size_t)posB * 40 + 16);
#pragma unroll
        for (int t = 0; t < 6; ++t) {
            float4 r; r.x=row[4*t+0]; r.y=row[4*t+1]; r.z=row[4*t+2]; r.w=row[4*t+3];
            vp[t] = r;
        }
    }
}

__global__ __launch_bounds__(256) void node_reduce(
    const int*   __restrict__ start,
    const float* __restrict__ exbuf,
    const float* __restrict__ vbuf,
    float* __restrict__ out, int N)
{
    const int wave = threadIdx.x >> 6;
    const int lane = threadIdx.x & 63;
    const int n = blockIdx.x * 4 + wave;
    if (n >= N) return;
    const int r0 = start[n], r1 = start[n + 1];
    float z = 0.f, comp = 0.f;
    for (int r = r0; r < r1; ++r) {
        z += exbuf[r];
        if (lane < 40) comp += vbuf[(size_t)r * 40 + lane];
    }
    if (lane < 40)
        out[(size_t)n * 40 + lane] = (z > 0.f) ? comp * rsqrtf(z) : 0.f;
}

extern "C" void kernel_launch(void* const* d_in, const int* in_sizes, int n_in,
                              void* d_out, int out_size, void* d_ws, size_t ws_size,
                              hipStream_t stream) {
    const float* node_ft      = (const float*)d_in[0];
    const int*   edge_index   = (const int*)  d_in[1];
    const float* edge_sh      = (const float*)d_in[2];
    const float* edge_scalars = (const float*)d_in[3];
    const float* w_q_s        = (const float*)d_in[4];
    const float* w_q_v        = (const float*)d_in[5];
    const float* fck_w1       = (const float*)d_in[6];
    const float* fck_w2       = (const float*)d_in[7];
    const float* fcv_w1       = (const float*)d_in[8];
    const float* fcv_w2       = (const float*)d_in[9];
    const float* wdot_s       = (const float*)d_in[10];
    const float* wdot_v       = (const float*)d_in[11];

    const int N = in_sizes[0] / 40;
    const int E = in_sizes[2] / 4;

    float* ws    = (float*)d_ws;
    float* qd    = ws;                               // N*20
    int*   cnt   = (int*)(ws + (size_t)N * 20);      // N
    int*   start = cnt + N;                          // N+1
    int*   curs  = start + N + 1;                    // N
    int*   flg   = curs + N;                         // 1
    size_t off   = (size_t)N * 20 + N + (N + 1) + N + 1;
    off = (off + 3) & ~(size_t)3;                    // 16B align
    float*    exbuf  = ws + off;                     // E
    float*    sabuf  = exbuf + E;                    // E
    int*      posbuf = (int*)(sabuf + E);            // E
    unsigned* t3buf  = (unsigned*)(posbuf + E);      // E*4 (16B-aligned: E%4==0)
    float*    vbuf   = (float*)(t3buf + (size_t)E * 4);  // E*40

    float* out = (float*)d_out;

    const int NB2 = (E + 2*BS - 1) / (2*BS);

    hipLaunchKernelGGL(node_pre, dim3((N + 255) / 256), dim3(256), 0, stream,
                       node_ft, edge_index, w_q_s, w_q_v, wdot_s, wdot_v,
                       qd, cnt, flg, N, E);
    hipLaunchKernelGGL(count_edges, dim3((E + 255) / 256), dim3(256), 0, stream,
                       edge_index, cnt, flg, E);
    hipLaunchKernelGGL(scan_kernel, dim3(1), dim3(1024), 0, stream,
                       cnt, start, curs, N);
    hipLaunchKernelGGL(edge_k, dim3(NB2), dim3(BS), 0, stream,
                       node_ft, edge_index, edge_sh, edge_scalars,
                       fck_w1, fck_w2, qd, curs, exbuf, sabuf, posbuf, flg, N, E);
    hipLaunchKernelGGL(edge_v_a, dim3(NB2), dim3(BS), 0, stream,
                       node_ft, edge_index, edge_sh, edge_scalars,
                       fcv_w1, fcv_w2, sabuf, posbuf, t3buf, vbuf, flg, E);
    hipLaunchKernelGGL(edge_v_b, dim3(NB2), dim3(BS), 0, stream,
                       node_ft, edge_index, edge_sh, edge_scalars,
                       fcv_w1, fcv_w2, sabuf, posbuf, t3buf, vbuf, flg, E);
    hipLaunchKernelGGL(node_reduce, dim3((N + 3) / 4), dim3(256), 0, stream,
                       start, exbuf, vbuf, out, N);
}